// Round 6
// baseline (11592.690 us; speedup 1.0000x reference)
//
#include <hip/hip_runtime.h>
#include <hip/hip_bf16.h>
#include <hip/hip_cooperative_groups.h>

namespace cg = cooperative_groups;

#define BB 128   // batch
#define LL 512   // seq len
#define HH 2048  // hidden
#define EE 128   // embed
#define VV 96    // vocab
#define BBHH (BB * HH)
#define NBLK 256

typedef short bf16x8 __attribute__((ext_vector_type(8)));
typedef float f32x4 __attribute__((ext_vector_type(4)));

__device__ __forceinline__ unsigned short f2bf(float f) {
    union { float f; unsigned int u; } c; c.f = f;
    unsigned int u = c.u;
    return (unsigned short)((u + 0x7FFFu + ((u >> 16) & 1u)) >> 16);  // RNE
}

__device__ __forceinline__ unsigned long long ld_dev(const unsigned long long* p) {
    return __hip_atomic_load(p, __ATOMIC_RELAXED, __HIP_MEMORY_SCOPE_AGENT);
}
__device__ __forceinline__ void st_dev(unsigned short* p, unsigned short v) {
    __hip_atomic_store(p, v, __ATOMIC_RELAXED, __HIP_MEMORY_SCOPE_AGENT);
}
__device__ __forceinline__ unsigned ld_dev32(const unsigned* p) {
    return __hip_atomic_load(p, __ATOMIC_RELAXED, __HIP_MEMORY_SCOPE_AGENT);
}
__device__ __forceinline__ void st_dev32(unsigned* p, unsigned v) {
    __hip_atomic_store(p, v, __ATOMIC_RELAXED, __HIP_MEMORY_SCOPE_AGENT);
}

// Contention-free, fence-free grid barrier.
// Arrival: after __syncthreads (each wave's vmcnt drained -> its sc1 h-stores
// acked at the coherence point), tid 0 sc1-stores the epoch into this block's
// OWN slot — no atomic RMW, no same-line serialization (R4/5's 256-way
// contended atomicAdd cost ~18 us/step).
// Wait: thread tid busy-polls slots[tid] with sc1 loads (bypass stale per-XCD
// L2) — all 256 arrivals observed in a single stage, no relay.
// Slots are written only by their owning block, monotonically -> no reuse
// hazard; a block can run at most one barrier ahead.
__device__ __forceinline__ void gridbar(unsigned* slots, unsigned epoch,
                                        int bid, int tid) {
    __syncthreads();   // s_waitcnt vmcnt(0) lgkmcnt(0) + s_barrier per wave
    if (tid == 0) {
        asm volatile("s_waitcnt vmcnt(0)" ::: "memory");
        st_dev32(&slots[bid], epoch);
    }
    while (ld_dev32(&slots[tid]) < epoch) { /* busy spin */ }
    __syncthreads();
}

// Persistent cooperative RNN kernel. Grid = 256 blocks = 2 bm (64 batch rows)
// x 128 bn (16 hidden cols). W_hh slice (16x2048 bf16 = 64 KB) in LDS in MFMA
// B-fragment-linear order, loaded once. h ping-pongs between two 512 KB global
// buffers, accessed with device-scope (sc1) ops; one slot-barrier per step.
// Logits computed in-kernel, one step behind, by duty blocks (bn<6). Next
// step's projE values are prefetched before the barrier.
__global__ __launch_bounds__(256, 1)
void rnn_coop(const int* __restrict__ x, const float* __restrict__ hidden,
              const float* __restrict__ emb, const float* __restrict__ W_xh,
              const float* __restrict__ W_hh, const float* __restrict__ b_h,
              const float* __restrict__ W_hy, const float* __restrict__ b_y,
              float* __restrict__ projE, unsigned short* __restrict__ w_hy_frag,
              unsigned short* __restrict__ hbuf, unsigned* __restrict__ bar,
              float* __restrict__ out_logits, float* __restrict__ out_final)
{
    __shared__ __align__(16) unsigned short ldsB[4096 * 8];  // 64 KB

    const int tid  = threadIdx.x;
    const int bid  = blockIdx.x;
    const int gtid = bid * 256 + tid;   // 0..65535

    const int bm = bid >> 7;            // 0..1
    const int bn = bid & 127;           // 0..127
    const int m0 = bm * 64;
    const int n0 = bn * 16;

    // ---- barrier slots = 0 (ws is re-poisoned 0xAA before every call) ----
    if (bid == 0) st_dev32(&bar[tid], 0u);   // sc1 write-through

    // ---- LDS fill: W_hh slice -> bf16, fragment-linear (one-time) ----
    for (int c = tid; c < 4096; c += 256) {
        int i  = c >> 6;
        int l  = c & 63;
        int nl = l & 15;
        int qq = l >> 4;
        const float* src = W_hh + (size_t)(n0 + nl) * HH + (size_t)i * 32 + qq * 8;
        unsigned short tmp[8];
        #pragma unroll
        for (int j = 0; j < 8; ++j) tmp[j] = f2bf(src[j]);
        #pragma unroll
        for (int j = 0; j < 8; ++j) ldsB[c * 8 + j] = tmp[j];
    }

    // ---- projE[v][h] = b_h[h] + emb[v][:] . W_xh[h][:]  (f32, exact) ----
    for (int i = gtid; i < VV * HH; i += 65536) {
        int v  = i >> 11;
        int hc = i & (HH - 1);
        const float4* ep = (const float4*)(emb + (size_t)v * EE);
        const float4* wp = (const float4*)(W_xh + (size_t)hc * EE);
        float s = b_h[hc];
        #pragma unroll 8
        for (int e = 0; e < EE / 4; ++e) {
            float4 a = ep[e], b = wp[e];
            s += a.x * b.x + a.y * b.y + a.z * b.z + a.w * b.w;
        }
        projE[i] = s;
    }
    // ---- W_hy -> bf16, fragment-linear per 16-vocab tile ----
    for (int idx = gtid; idx < VV * HH; idx += 65536) {
        int vt  = idx >> 15;            // /32768
        int rem = idx & 32767;
        int c   = rem >> 3;
        int j   = rem & 7;
        int l   = c & 63;
        int i   = c >> 6;
        int v   = vt * 16 + (l & 15);
        int k   = i * 32 + (l >> 4) * 8 + j;
        w_hy_frag[idx] = f2bf(W_hy[(size_t)v * HH + k]);
    }
    // ---- h_0 (bf16) into ping buffer 0 ----
    for (int i = gtid; i < BBHH; i += 65536) hbuf[i] = f2bf(hidden[i]);

    __syncthreads();
    cg::grid_group grid = cg::this_grid();
    __threadfence();
    grid.sync();   // one-time: publishes setup writes (incl. zeroed slots)

    const int w    = tid >> 6;      // wave 0..3 -> rows m0 + w*16
    const int lane = tid & 63;
    const int col  = lane & 15;
    const int q    = lane >> 4;
    const int am   = m0 + w * 16 + col;    // A-fragment row (batch index)
    const int n    = n0 + col;             // output hidden column
    const bf16x8* ldsB8 = (const bf16x8*)ldsB;

    const bool duty = (bn < 6);
    const int  v0   = bn * 16;             // duty vocab tile base
    const bf16x8* Hyp = (const bf16x8*)w_hy_frag + (size_t)bn * 4096 + lane;
    const float by = duty ? b_y[v0 + col] : 0.f;

    // per-thread epilogue rows + first-step prefetch of projE values
    int   mrow[4];
    float pv[4];
    #pragma unroll
    for (int r = 0; r < 4; ++r) {
        mrow[r] = m0 + w * 16 + q * 4 + r;
        int tok = x[(size_t)mrow[r] * LL];
        pv[r]   = projE[(size_t)tok * HH + n];
    }

    for (int t = 0; t < LL; ++t) {
        const unsigned short* hp = hbuf + (size_t)(t & 1) * BBHH;
        unsigned short* hn       = hbuf + (size_t)((t + 1) & 1) * BBHH;
        const unsigned long long* Ap8 =
            (const unsigned long long*)(hp + (size_t)am * HH) + q * 2;

        f32x4 acc  = {0.f, 0.f, 0.f, 0.f};
        f32x4 accL = {0.f, 0.f, 0.f, 0.f};
        if (duty && t > 0) {
            #pragma unroll 4
            for (int i = 0; i < 64; ++i) {
                union { unsigned long long u[2]; bf16x8 v; } A;
                A.u[0] = ld_dev(Ap8 + (size_t)i * 8);
                A.u[1] = ld_dev(Ap8 + (size_t)i * 8 + 1);
                bf16x8 b  = ldsB8[i * 64 + lane];
                bf16x8 bl = Hyp[i * 64];
                acc  = __builtin_amdgcn_mfma_f32_16x16x32_bf16(A.v, b,  acc,  0, 0, 0);
                accL = __builtin_amdgcn_mfma_f32_16x16x32_bf16(A.v, bl, accL, 0, 0, 0);
            }
        } else {
            #pragma unroll 8
            for (int i = 0; i < 64; ++i) {
                union { unsigned long long u[2]; bf16x8 v; } A;
                A.u[0] = ld_dev(Ap8 + (size_t)i * 8);
                A.u[1] = ld_dev(Ap8 + (size_t)i * 8 + 1);
                bf16x8 b = ldsB8[i * 64 + lane];
                acc = __builtin_amdgcn_mfma_f32_16x16x32_bf16(A.v, b, acc, 0, 0, 0);
            }
        }

        // h epilogue: C/D layout col=lane&15, row=(lane>>4)*4+r
        #pragma unroll
        for (int r = 0; r < 4; ++r) {
            float v = acc[r] + pv[r];
            v = fminf(fmaxf(v, -15.f), 15.f);
            float e2 = __expf(2.f * v);
            float hv = (e2 - 1.f) / (e2 + 1.f);   // tanh
            st_dev(&hn[(size_t)mrow[r] * HH + n], f2bf(hv));
            if (t == LL - 1) out_final[(size_t)mrow[r] * HH + n] = hv;
        }
        // logits epilogue for h_t -> position t-1
        if (duty && t > 0) {
            #pragma unroll
            for (int r = 0; r < 4; ++r) {
                out_logits[(size_t)mrow[r] * (LL * VV) + (size_t)(t - 1) * VV + v0 + col]
                    = accL[r] + by;
            }
        }
        // prefetch next step's projE values (latency hides behind the barrier)
        if (t + 1 < LL) {
            #pragma unroll
            for (int r = 0; r < 4; ++r) {
                int tok = x[(size_t)mrow[r] * LL + t + 1];
                pv[r]   = projE[(size_t)tok * HH + n];
            }
        }
        gridbar(bar, (unsigned)(t + 1), bid, tid);
    }

    // logits for h_LL -> position LL-1 (final h is in ping buffer LL&1 = 0)
    if (duty) {
        const unsigned long long* Ap8 =
            (const unsigned long long*)(hbuf + (size_t)am * HH) + q * 2;
        f32x4 accL = {0.f, 0.f, 0.f, 0.f};
        #pragma unroll 8
        for (int i = 0; i < 64; ++i) {
            union { unsigned long long u[2]; bf16x8 v; } A;
            A.u[0] = ld_dev(Ap8 + (size_t)i * 8);
            A.u[1] = ld_dev(Ap8 + (size_t)i * 8 + 1);
            bf16x8 bl = Hyp[i * 64];
            accL = __builtin_amdgcn_mfma_f32_16x16x32_bf16(A.v, bl, accL, 0, 0, 0);
        }
        #pragma unroll
        for (int r = 0; r < 4; ++r) {
            int m = m0 + w * 16 + q * 4 + r;
            out_logits[(size_t)m * (LL * VV) + (size_t)(LL - 1) * VV + v0 + col]
                = accL[r] + by;
        }
    }
}

extern "C" void kernel_launch(void* const* d_in, const int* in_sizes, int n_in,
                              void* d_out, int out_size, void* d_ws, size_t ws_size,
                              hipStream_t stream) {
    const int*   x      = (const int*)  d_in[0];
    const float* hidden = (const float*)d_in[1];
    const float* emb    = (const float*)d_in[2];
    const float* W_xh   = (const float*)d_in[3];
    const float* W_hh   = (const float*)d_in[4];
    const float* b_h    = (const float*)d_in[5];
    const float* W_hy   = (const float*)d_in[6];
    const float* b_y    = (const float*)d_in[7];

    float* out_logits = (float*)d_out;                          // [B][L][V]
    float* out_final  = out_logits + (size_t)BB * LL * VV;      // [B][H]

    // workspace: 768 KB projE + 384 KB w_hy_frag + 1 MB h ping-pong + slots
    char* ws = (char*)d_ws;
    float* projE              = (float*)ws;
    unsigned short* w_hy_frag = (unsigned short*)(ws + 786432);
    unsigned short* hbuf      = (unsigned short*)(ws + 786432 + 393216);
    unsigned* bar             = (unsigned*)(ws + 786432 + 393216 + 2 * BBHH * 2);

    void* args[] = { (void*)&x, (void*)&hidden, (void*)&emb, (void*)&W_xh,
                     (void*)&W_hh, (void*)&b_h, (void*)&W_hy, (void*)&b_y,
                     (void*)&projE, (void*)&w_hy_frag, (void*)&hbuf,
                     (void*)&bar, (void*)&out_logits, (void*)&out_final };
    hipLaunchCooperativeKernel((const void*)rnn_coop, dim3(256), dim3(256),
                               args, 0, stream);
}